// Round 2
// baseline (100207.343 us; speedup 1.0000x reference)
//
#include <hip/hip_runtime.h>
#include <stdint.h>

// ---------------------------------------------------------------------------
// Seq2seq LSTM autoencoder (T=4096, H=1024, L=2), fp32 end-to-end.
// Round 5: latency-lean re-gearing of the fused layer-pair scan.
//   - 64 blocks x 1024 threads per layer (16 h-rows/block); pair kernel =
//     128 blocks -> 1 block/CU (no CU sharing, vs 2/CU in round 4).
//   - h exchange: one u64 atomic load/store per element (tagged dword pair
//     in a single global_load_dwordx2) instead of 8 scalar dword atomics.
//     Memory layout of the tagged stream is bit-identical to round 4.
//   - Each thread polls exactly ONE element (its own); 64 producer blocks
//     instead of 256 shrinks the per-step straggler tail.
//   - Poll loop spins nearly free-running (s_sleep(1) every 1024 iters);
//     panic escape preserved for true-deadlock debuggability.
//   - Redundant 3rd __syncthreads per step removed (gl[] is protected by
//     the next iteration's first barrier).
// Schedule unchanged: pair(enc L0, enc L1) -> pair(dec L0, dec L1) -> proj.
// Deadlock-free: layer-A blocks never wait on layer-B; within a layer all
// 64 blocks are trivially co-resident (128 blocks <= 256 CUs).
// ---------------------------------------------------------------------------

#define T_STEPS 4096
#define H_DIM   1024
#define SLOT_U64 1024             // 1024 elements x (2 tagged dwords = 1 u64)
#define SLOT_DW  2048
#define NSLOT   4097
#define M1 0x7E57u
#define M2 0x7E58u
#define PANIC_ITERS (1u<<25)

using u32 = uint32_t;
using u64 = unsigned long long;

static __device__ __forceinline__ float sigf(float x){ return 1.0f/(1.0f+__expf(-x)); }
static __device__ __forceinline__ float tanh_f(float x){
  x = fminf(20.f, fmaxf(-20.f, x));
  float e = __expf(-2.f*x);
  return (1.f-e)/(1.f+e);
}

static __device__ __forceinline__ bool tag_ok(u64 v, u32 magic){
  return ((((u32)(v>>16))&0xFFFFu)==magic) & (((u32)(v>>48))==magic);
}
static __device__ __forceinline__ float untag1(u64 v){
  return __uint_as_float( (((u32)v)&0xFFFFu) | (((u32)(v>>32))<<16) );
}
static __device__ __forceinline__ u64 tag1(u32 magic, float h){
  u32 b=__float_as_uint(h);
  u64 lo = (u64)((magic<<16)|(b&0xFFFFu));
  u64 hi = ((u64)((magic<<16)|(b>>16)))<<32;
  return hi|lo;
}

// Poll one tagged element until valid; deposit fp32 into *dst (LDS).
static __device__ __forceinline__ void poll1(const u64* __restrict__ q, u32 magic,
                                             float* dst, u32* panic){
  u64 v=0; u32 it=0;
  for(;;){
    v=__hip_atomic_load(q,__ATOMIC_RELAXED,__HIP_MEMORY_SCOPE_AGENT);
    if(tag_ok(v,magic)) break;
    if(((++it)&1023u)==0u){
      if(__hip_atomic_load(panic,__ATOMIC_RELAXED,__HIP_MEMORY_SCOPE_AGENT)==0xDEADBEEFu) break;
      if(it>PANIC_ITERS){ __hip_atomic_store(panic,0xDEADBEEFu,__ATOMIC_RELAXED,__HIP_MEMORY_SCOPE_AGENT); break; }
      __builtin_amdgcn_s_sleep(1);
    }
  }
  *dst = untag1(v);
}

// Concurrent dual-element poll (modes 1/3): both loads stay in flight.
static __device__ __forceinline__ void poll2(const u64* __restrict__ qa, u32 mA,
                                             const u64* __restrict__ qb, u32 mB,
                                             float* da, float* db, u32* panic){
  u64 va=0, vb=0; bool okA=false, okB=false; u32 it=0;
  for(;;){
    if(!okA) va=__hip_atomic_load(qa,__ATOMIC_RELAXED,__HIP_MEMORY_SCOPE_AGENT);
    if(!okB) vb=__hip_atomic_load(qb,__ATOMIC_RELAXED,__HIP_MEMORY_SCOPE_AGENT);
    okA = okA || tag_ok(va,mA);
    okB = okB || tag_ok(vb,mB);
    if(okA & okB) break;
    if(((++it)&1023u)==0u){
      if(__hip_atomic_load(panic,__ATOMIC_RELAXED,__HIP_MEMORY_SCOPE_AGENT)==0xDEADBEEFu) break;
      if(it>PANIC_ITERS){ __hip_atomic_store(panic,0xDEADBEEFu,__ATOMIC_RELAXED,__HIP_MEMORY_SCOPE_AGENT); break; }
      __builtin_amdgcn_s_sleep(1);
    }
  }
  *da = untag1(va);
  *db = untag1(vb);
}

// One LSTM layer over T steps. kb = block index within the layer (0..63).
// Block owns h-rows hr0..hr0+15. 16 waves: wave w -> gate g=w>>2, row quad
// q=w&3 (gate rows g*1024 + hr0 + q*4 .. +3); lane l = one 32-col segment of
// the concatenated K=2048 [W_ih | W_hh] dot (lanes 0-31 input, 32-63 h).
// mode 0: input = raw x.  mode 1/3: input = tagged stream (m_in).
// mode 2: input = CONSTANT tagged slot (staged once).
static __device__ __forceinline__ void lstm_scan_body(
    int kb, int tid, float* st, float* gl,
    const float* __restrict__ xin,
    const u64*  __restrict__ instream,
    u64*        __restrict__ own,
    u32 m_in, u32 m_own,
    const float* __restrict__ Wih, const float* __restrict__ Whh,
    const float* __restrict__ bih, const float* __restrict__ bhh,
    const float* __restrict__ c0,      // null -> zeros
    float*       __restrict__ cout,    // final c per row
    const u64*  __restrict__ h0slot,   // tagged slot holding h0; null -> zeros
    float*       __restrict__ fh_out,  // if non-null: write final h (enc L1)
    u32* __restrict__ panic,
    int mode)
{
  const int hr0=kb*16;
  const int w=tid>>6, l=tid&63;
  const int g=w>>2, q=w&3;
  const int grow0=(g<<10)+hr0+(q<<2);      // first of 4 owned gate rows
  const int fb  = tid + 4*(tid>>5);        // stage word, IN part (1 elem/thread)
  const int fbH = 1152+fb;                 // stage word, H part
  const int sb  = l*36;                    // dot segment word base

  // fp32 weights in registers: 4 gate rows x 32-col segment
  float wr0[32],wr1[32],wr2[32],wr3[32];
  {
    const float* srcb = (l<32) ? Wih + (size_t)grow0*H_DIM + l*32
                               : Whh + (size_t)grow0*H_DIM + (l-32)*32;
    #pragma unroll
    for(int i=0;i<8;i++){
      float4 a0=*(const float4*)(srcb + i*4);
      float4 a1=*(const float4*)(srcb + 1024 + i*4);
      float4 a2=*(const float4*)(srcb + 2048 + i*4);
      float4 a3=*(const float4*)(srcb + 3072 + i*4);
      wr0[4*i]=a0.x; wr0[4*i+1]=a0.y; wr0[4*i+2]=a0.z; wr0[4*i+3]=a0.w;
      wr1[4*i]=a1.x; wr1[4*i+1]=a1.y; wr1[4*i+2]=a1.z; wr1[4*i+3]=a1.w;
      wr2[4*i]=a2.x; wr2[4*i+1]=a2.y; wr2[4*i+2]=a2.z; wr2[4*i+3]=a2.w;
      wr3[4*i]=a3.x; wr3[4*i+1]=a3.y; wr3[4*i+2]=a3.z; wr3[4*i+3]=a3.w;
    }
  }

  float bI=0,bF=0,bG=0,bO=0,c_st=0.f,h_st=0.f;   // valid for tid<16
  if(tid<16){
    int o=hr0+tid;
    bI=bih[o]       + bhh[o];
    bF=bih[o+1024]  + bhh[o+1024];
    bG=bih[o+2048]  + bhh[o+2048];
    bO=bih[o+3072]  + bhh[o+3072];
    if(c0)     c_st=c0[o];
    if(h0slot) h_st=untag1(h0slot[o]);
    __hip_atomic_store(own+o, tag1(m_own,h_st), __ATOMIC_RELAXED,__HIP_MEMORY_SCOPE_AGENT);
  }
  if(mode==2){                                  // constant input: stage once
    st[fb]=untag1(instream[tid]);
  }

  for(int t=0;t<T_STEPS;++t){
    if(mode==0){
      st[fb]=xin[(size_t)t*H_DIM + tid];
      poll1(own + (size_t)t*SLOT_U64 + tid, m_own, st+fbH, panic);
    } else if(mode==2){
      poll1(own + (size_t)t*SLOT_U64 + tid, m_own, st+fbH, panic);
    } else {
      poll2(instream + (size_t)(t+1)*SLOT_U64 + tid, m_in,
            own      + (size_t)t*SLOT_U64     + tid, m_own,
            st+fb, st+fbH, panic);
    }
    __syncthreads();
    float p0=0.f,p1=0.f,p2=0.f,p3=0.f;
    #pragma unroll
    for(int i=0;i<8;i++){
      float4 s=*(const float4*)(st+sb+i*4);
      p0+=s.x*wr0[4*i]+s.y*wr0[4*i+1]+s.z*wr0[4*i+2]+s.w*wr0[4*i+3];
      p1+=s.x*wr1[4*i]+s.y*wr1[4*i+1]+s.z*wr1[4*i+2]+s.w*wr1[4*i+3];
      p2+=s.x*wr2[4*i]+s.y*wr2[4*i+1]+s.z*wr2[4*i+2]+s.w*wr2[4*i+3];
      p3+=s.x*wr3[4*i]+s.y*wr3[4*i+1]+s.z*wr3[4*i+2]+s.w*wr3[4*i+3];
    }
    #pragma unroll
    for(int off=32;off;off>>=1){
      p0+=__shfl_down(p0,off,64); p1+=__shfl_down(p1,off,64);
      p2+=__shfl_down(p2,off,64); p3+=__shfl_down(p3,off,64);
    }
    if(l==0){ gl[w*4+0]=p0; gl[w*4+1]=p1; gl[w*4+2]=p2; gl[w*4+3]=p3; }
    __syncthreads();
    if(tid<16){
      // gl[g*16 + r]: gate g partial for h-row r (r = tid)
      float gi=bI+gl[tid], gf=bF+gl[16+tid], gg=bG+gl[32+tid], go=bO+gl[48+tid];
      c_st = sigf(gf)*c_st + sigf(gi)*tanh_f(gg);
      h_st = sigf(go)*tanh_f(c_st);
      __hip_atomic_store(own + (size_t)(t+1)*SLOT_U64 + hr0 + tid,
                         tag1(m_own,h_st), __ATOMIC_RELAXED,__HIP_MEMORY_SCOPE_AGENT);
      if(t==T_STEPS-1){
        cout[hr0+tid]=c_st;
        if(fh_out) fh_out[hr0+tid]=h_st;
      }
    }
    // no 3rd barrier: gl reads above complete before any thread passes the
    // NEXT iteration's first __syncthreads, which precedes all gl writes.
  }
}

// Fused layer pair: blocks [0,64) = layer A, [64,128) = layer B.
// B consumes A's stream with 1-step skew. A never waits on B.
__global__ __launch_bounds__(1024,1) void lstm_scan_pair(
    const float* __restrict__ xinA,
    const u64*  __restrict__ insA, u64* __restrict__ ownA, u32 miA, u32 moA,
    const float* __restrict__ WihA, const float* __restrict__ WhhA,
    const float* __restrict__ bihA, const float* __restrict__ bhhA,
    const float* __restrict__ c0A, float* __restrict__ coutA,
    const u64*  __restrict__ h0A, float* __restrict__ fhA, int modeA,
    const u64*  __restrict__ insB, u64* __restrict__ ownB, u32 miB, u32 moB,
    const float* __restrict__ WihB, const float* __restrict__ WhhB,
    const float* __restrict__ bihB, const float* __restrict__ bhhB,
    const float* __restrict__ c0B, float* __restrict__ coutB,
    const u64*  __restrict__ h0B, float* __restrict__ fhB, int modeB,
    u32* __restrict__ panic)
{
  __shared__ __align__(16) float st[2304];
  __shared__ float gl[64];
  const int b=blockIdx.x, tid=threadIdx.x;
  if(b<64){
    lstm_scan_body(b, tid, st, gl, xinA, insA, ownA, miA, moA,
                   WihA, WhhA, bihA, bhhA, c0A, coutA, h0A, fhA, panic, modeA);
  } else {
    lstm_scan_body(b-64, tid, st, gl, nullptr, insB, ownB, miB, moB,
                   WihB, WhhB, bihB, bhhB, c0B, coutB, h0B, fhB, panic, modeB);
  }
}

// out[(4095-tp), o] = leaky( sum_k oW[o,k] * h1d[tp][k] + ob[o] )
__global__ __launch_bounds__(256) void proj_out(
    const u64* __restrict__ SB, const float* __restrict__ oW,
    const float* __restrict__ ob, float* __restrict__ out)
{
  __shared__ __align__(16) float hb[1024];
  const int tp=blockIdx.x, tid=threadIdx.x;
  #pragma unroll
  for(int j=0;j<4;j++)
    hb[tid*4+j] = untag1(SB[(size_t)(tp+1)*SLOT_U64 + tid*4 + j]);
  __syncthreads();
  #pragma unroll
  for(int j=0;j<4;j++){
    int o = tid + 256*j;
    const float* wr = oW + (size_t)o*H_DIM;
    float acc=0.f;
    for(int k=0;k<1024;k+=4){
      float4 wv=*(const float4*)(wr+k);
      acc += wv.x*hb[k]+wv.y*hb[k+1]+wv.z*hb[k+2]+wv.w*hb[k+3];
    }
    acc += ob[o];
    acc = acc>0.f ? acc : 0.01f*acc;
    out[(size_t)(4095-tp)*H_DIM + o]=acc;
  }
}

extern "C" void kernel_launch(void* const* d_in, const int* in_sizes, int n_in,
                              void* d_out, int out_size, void* d_ws, size_t ws_size,
                              hipStream_t stream) {
  const float* x    = (const float*)d_in[0];
  const float* eWih = (const float*)d_in[1];
  const float* eWhh = (const float*)d_in[2];
  const float* ebih = (const float*)d_in[3];
  const float* ebhh = (const float*)d_in[4];
  const float* dWih = (const float*)d_in[5];
  const float* dWhh = (const float*)d_in[6];
  const float* dbih = (const float*)d_in[7];
  const float* dbhh = (const float*)d_in[8];
  const float* oW   = (const float*)d_in[9];
  const float* ob   = (const float*)d_in[10];
  float* out = (float*)d_out;
  u32* ws = (u32*)d_ws;

  const size_t REGION = (size_t)NSLOT*SLOT_DW;     // in dwords
  u64*   SA    = (u64*)ws;
  u64*   SB    = (u64*)(ws + REGION);
  float* CA    = (float*)(ws + 2*REGION);          // 2048 floats: enc c finals
  u32*   panic = ws + 2*REGION + 2048;
  const size_t LSTRIDE = (size_t)4096*1024;        // per-layer weight stride

  // clear tags + c buffer + panic
  size_t clr_bytes = (2*REGION + 2048 + 64)*4;
  hipMemsetAsync(d_ws, 0, clr_bytes, stream);

  // Phase 1: enc L0 (mode 0, x -> SA/M1, zero init) || enc L1 (mode 1,
  // SA/M1 -> SB/M1, zero init, writes final_hidden).
  lstm_scan_pair<<<128,1024,0,stream>>>(
      x, nullptr, SA, 0u, M1,
      eWih, eWhh, ebih, ebhh,
      nullptr, CA, nullptr, nullptr, 0,
      SA, SB, M1, M1,
      eWih+LSTRIDE, eWhh+LSTRIDE, ebih+4096, ebhh+4096,
      nullptr, CA+1024, nullptr, out + (size_t)T_STEPS*H_DIM, 1,
      panic);

  // Phase 2: dec L0 (mode 2, const input = final_hidden slot SB[4096],
  // stream SA reused with M2, init = enc L0 finals) || dec L1 (mode 3,
  // SA/M2 -> SB/M2, init = enc L1 finals).
  lstm_scan_pair<<<128,1024,0,stream>>>(
      nullptr, SB + (size_t)4096*SLOT_U64, SA, 0u, M2,
      dWih, dWhh, dbih, dbhh,
      CA, CA, SA + (size_t)4096*SLOT_U64, nullptr, 2,
      SA, SB, M2, M2,
      dWih+LSTRIDE, dWhh+LSTRIDE, dbih+4096, dbhh+4096,
      CA+1024, CA+1024, SB + (size_t)4096*SLOT_U64, nullptr, 3,
      panic);

  // projection + leaky ReLU + flip
  proj_out<<<4096,256,0,stream>>>(SB, oW, ob, out);
}

// Round 3
// 25274.663 us; speedup vs baseline: 3.9647x; 3.9647x over previous
//
#include <hip/hip_runtime.h>
#include <stdint.h>

// ---------------------------------------------------------------------------
// Seq2seq LSTM autoencoder (T=4096, H=1024, L=2), fp32 end-to-end.
// Round 6: fix round-5's register spill while keeping its wins.
//   Round-5 post-mortem: 1024-thr blocks -> 4 waves/SIMD -> 128 VGPR/wave;
//   the 128 weight floats/thread spilled to scratch and were re-read every
//   step (FETCH 0.78 GB -> 76.7 GB, VGPR_Count 64). Geometry here:
//   - 128 blocks x 512 threads per layer (8 h-rows/block); pair = 256
//     blocks -> 1 block/CU, 8 waves/block -> 2 waves/SIMD -> 256 VGPR
//     budget/wave: 128 weight floats + overhead fit (round 4 proved it).
//   - h exchange: one u64 atomic load/store per element (tagged dword
//     pair); each thread polls its own 2 IN + 2 H elements, all four
//     loads kept in flight. Stream layout bit-identical to rounds 4/5.
//   - Poll cadence: s_sleep(4) per retry (round-4 proven; free-running
//     spin is unnecessary once registers are intact).
//   - 2 barriers/step (3rd elided; gl[] protected by next-iter barrier).
// Schedule unchanged: pair(enc L0, enc L1) -> pair(dec L0, dec L1) -> proj.
// Deadlock-free: layer-A blocks never wait on layer-B; 256 blocks = 256 CUs.
// ---------------------------------------------------------------------------

#define T_STEPS 4096
#define H_DIM   1024
#define SLOT_U64 1024             // 1024 elements x (2 tagged dwords = 1 u64)
#define SLOT_DW  2048
#define NSLOT   4097
#define M1 0x7E57u
#define M2 0x7E58u
#define PANIC_ITERS (1u<<25)

using u32 = uint32_t;
using u64 = unsigned long long;

static __device__ __forceinline__ float sigf(float x){ return 1.0f/(1.0f+__expf(-x)); }
static __device__ __forceinline__ float tanh_f(float x){
  x = fminf(20.f, fmaxf(-20.f, x));
  float e = __expf(-2.f*x);
  return (1.f-e)/(1.f+e);
}

static __device__ __forceinline__ bool tag_ok(u64 v, u32 magic){
  return ((((u32)(v>>16))&0xFFFFu)==magic) & (((u32)(v>>48))==magic);
}
static __device__ __forceinline__ float untag1(u64 v){
  return __uint_as_float( (((u32)v)&0xFFFFu) | (((u32)(v>>32))<<16) );
}
static __device__ __forceinline__ u64 tag1(u32 magic, float h){
  u32 b=__float_as_uint(h);
  u64 lo = (u64)((magic<<16)|(b&0xFFFFu));
  u64 hi = ((u64)((magic<<16)|(b>>16)))<<32;
  return hi|lo;
}

// Poll 2 tagged elements (one u64 each) until valid; deposit into LDS.
static __device__ __forceinline__ void poll_h2(const u64* __restrict__ q,
                                               u32 magic, float* dst,
                                               u32* panic){
  u64 v0=0,v1=0; bool ok0=false,ok1=false; u32 it=0;
  for(;;){
    if(!ok0) v0=__hip_atomic_load(q,  __ATOMIC_RELAXED,__HIP_MEMORY_SCOPE_AGENT);
    if(!ok1) v1=__hip_atomic_load(q+1,__ATOMIC_RELAXED,__HIP_MEMORY_SCOPE_AGENT);
    ok0 = ok0 || tag_ok(v0,magic);
    ok1 = ok1 || tag_ok(v1,magic);
    if(ok0 & ok1) break;
    ++it;
    if((it & 255u)==0u){
      if(__hip_atomic_load(panic,__ATOMIC_RELAXED,__HIP_MEMORY_SCOPE_AGENT)==0xDEADBEEFu) break;
      if(it>PANIC_ITERS){ __hip_atomic_store(panic,0xDEADBEEFu,__ATOMIC_RELAXED,__HIP_MEMORY_SCOPE_AGENT); break; }
    }
    __builtin_amdgcn_s_sleep(4);
  }
  dst[0]=untag1(v0);
  dst[1]=untag1(v1);
}

// Poll 2 IN + 2 H tagged elements concurrently (modes 1/3).
static __device__ __forceinline__ void poll_in2h2(const u64* __restrict__ qa, u32 mA,
                                                  const u64* __restrict__ qb, u32 mB,
                                                  float* da, float* db, u32* panic){
  u64 a0=0,a1=0,b0=0,b1=0; bool oa0=false,oa1=false,ob0=false,ob1=false; u32 it=0;
  for(;;){
    if(!oa0) a0=__hip_atomic_load(qa,  __ATOMIC_RELAXED,__HIP_MEMORY_SCOPE_AGENT);
    if(!oa1) a1=__hip_atomic_load(qa+1,__ATOMIC_RELAXED,__HIP_MEMORY_SCOPE_AGENT);
    if(!ob0) b0=__hip_atomic_load(qb,  __ATOMIC_RELAXED,__HIP_MEMORY_SCOPE_AGENT);
    if(!ob1) b1=__hip_atomic_load(qb+1,__ATOMIC_RELAXED,__HIP_MEMORY_SCOPE_AGENT);
    oa0 = oa0 || tag_ok(a0,mA);
    oa1 = oa1 || tag_ok(a1,mA);
    ob0 = ob0 || tag_ok(b0,mB);
    ob1 = ob1 || tag_ok(b1,mB);
    if(oa0 & oa1 & ob0 & ob1) break;
    ++it;
    if((it & 255u)==0u){
      if(__hip_atomic_load(panic,__ATOMIC_RELAXED,__HIP_MEMORY_SCOPE_AGENT)==0xDEADBEEFu) break;
      if(it>PANIC_ITERS){ __hip_atomic_store(panic,0xDEADBEEFu,__ATOMIC_RELAXED,__HIP_MEMORY_SCOPE_AGENT); break; }
    }
    __builtin_amdgcn_s_sleep(4);
  }
  da[0]=untag1(a0); da[1]=untag1(a1);
  db[0]=untag1(b0); db[1]=untag1(b1);
}

// One LSTM layer over T steps. kb = block index within the layer (0..127).
// Block owns h-rows hr0..hr0+7. 8 waves: wave w -> gate g=w>>1, quad q=w&1
// (gate rows g*1024 + hr0 + q*4 .. +3); lane l = one 32-col segment of the
// concatenated K=2048 [W_ih | W_hh] dot (lanes 0-31 input, 32-63 h).
// Thread handles stream elements 2*tid, 2*tid+1 of both IN and H parts.
// mode 0: input = raw x.  mode 1/3: input = tagged stream (m_in).
// mode 2: input = CONSTANT tagged slot (staged once).
static __device__ __forceinline__ void lstm_scan_body(
    int kb, int tid, float* st, float* gl,
    const float* __restrict__ xin,
    const u64*  __restrict__ instream,
    u64*        __restrict__ own,
    u32 m_in, u32 m_own,
    const float* __restrict__ Wih, const float* __restrict__ Whh,
    const float* __restrict__ bih, const float* __restrict__ bhh,
    const float* __restrict__ c0,      // null -> zeros
    float*       __restrict__ cout,    // final c per row
    const u64*  __restrict__ h0slot,   // tagged slot holding h0; null -> zeros
    float*       __restrict__ fh_out,  // if non-null: write final h (enc L1)
    u32* __restrict__ panic,
    int mode)
{
  const int hr0=kb*8;
  const int w=tid>>6, l=tid&63;
  const int g=w>>1, q=w&1;
  const int grow0=(g<<10)+hr0+(q<<2);      // first of 4 owned gate rows
  const int e0 = 2*tid;                    // first owned stream element
  const int fb  = e0 + 4*(e0>>5);          // stage word, IN part (2 elems)
  const int fbH = 1152+fb;                 // stage word, H part
  const int sb  = l*36;                    // dot segment word base

  // fp32 weights in registers: 4 gate rows x 32-col segment
  float wr0[32],wr1[32],wr2[32],wr3[32];
  {
    const float* srcb = (l<32) ? Wih + (size_t)grow0*H_DIM + l*32
                               : Whh + (size_t)grow0*H_DIM + (l-32)*32;
    #pragma unroll
    for(int i=0;i<8;i++){
      float4 a0=*(const float4*)(srcb + i*4);
      float4 a1=*(const float4*)(srcb + 1024 + i*4);
      float4 a2=*(const float4*)(srcb + 2048 + i*4);
      float4 a3=*(const float4*)(srcb + 3072 + i*4);
      wr0[4*i]=a0.x; wr0[4*i+1]=a0.y; wr0[4*i+2]=a0.z; wr0[4*i+3]=a0.w;
      wr1[4*i]=a1.x; wr1[4*i+1]=a1.y; wr1[4*i+2]=a1.z; wr1[4*i+3]=a1.w;
      wr2[4*i]=a2.x; wr2[4*i+1]=a2.y; wr2[4*i+2]=a2.z; wr2[4*i+3]=a2.w;
      wr3[4*i]=a3.x; wr3[4*i+1]=a3.y; wr3[4*i+2]=a3.z; wr3[4*i+3]=a3.w;
    }
  }

  float bI=0,bF=0,bG=0,bO=0,c_st=0.f,h_st=0.f;   // valid for tid<8
  if(tid<8){
    int o=hr0+tid;
    bI=bih[o]       + bhh[o];
    bF=bih[o+1024]  + bhh[o+1024];
    bG=bih[o+2048]  + bhh[o+2048];
    bO=bih[o+3072]  + bhh[o+3072];
    if(c0)     c_st=c0[o];
    if(h0slot) h_st=untag1(h0slot[o]);
    __hip_atomic_store(own+o, tag1(m_own,h_st), __ATOMIC_RELAXED,__HIP_MEMORY_SCOPE_AGENT);
  }
  if(mode==2){                                  // constant input: stage once
    st[fb]  =untag1(instream[e0]);
    st[fb+1]=untag1(instream[e0+1]);
  }

  for(int t=0;t<T_STEPS;++t){
    if(mode==0){
      float2 xv=*(const float2*)(xin + (size_t)t*H_DIM + e0);
      st[fb]=xv.x; st[fb+1]=xv.y;
      poll_h2(own + (size_t)t*SLOT_U64 + e0, m_own, st+fbH, panic);
    } else if(mode==2){
      poll_h2(own + (size_t)t*SLOT_U64 + e0, m_own, st+fbH, panic);
    } else {
      poll_in2h2(instream + (size_t)(t+1)*SLOT_U64 + e0, m_in,
                 own      + (size_t)t*SLOT_U64     + e0, m_own,
                 st+fb, st+fbH, panic);
    }
    __syncthreads();
    float p0=0.f,p1=0.f,p2=0.f,p3=0.f;
    #pragma unroll
    for(int i=0;i<8;i++){
      float4 s=*(const float4*)(st+sb+i*4);
      p0+=s.x*wr0[4*i]+s.y*wr0[4*i+1]+s.z*wr0[4*i+2]+s.w*wr0[4*i+3];
      p1+=s.x*wr1[4*i]+s.y*wr1[4*i+1]+s.z*wr1[4*i+2]+s.w*wr1[4*i+3];
      p2+=s.x*wr2[4*i]+s.y*wr2[4*i+1]+s.z*wr2[4*i+2]+s.w*wr2[4*i+3];
      p3+=s.x*wr3[4*i]+s.y*wr3[4*i+1]+s.z*wr3[4*i+2]+s.w*wr3[4*i+3];
    }
    #pragma unroll
    for(int off=32;off;off>>=1){
      p0+=__shfl_down(p0,off,64); p1+=__shfl_down(p1,off,64);
      p2+=__shfl_down(p2,off,64); p3+=__shfl_down(p3,off,64);
    }
    if(l==0){ gl[w*4+0]=p0; gl[w*4+1]=p1; gl[w*4+2]=p2; gl[w*4+3]=p3; }
    __syncthreads();
    if(tid<8){
      // gl[g*8 + r]: gate g partial for block h-row r (r = tid)
      float gi=bI+gl[tid], gf=bF+gl[8+tid], gg=bG+gl[16+tid], go=bO+gl[24+tid];
      c_st = sigf(gf)*c_st + sigf(gi)*tanh_f(gg);
      h_st = sigf(go)*tanh_f(c_st);
      __hip_atomic_store(own + (size_t)(t+1)*SLOT_U64 + hr0 + tid,
                         tag1(m_own,h_st), __ATOMIC_RELAXED,__HIP_MEMORY_SCOPE_AGENT);
      if(t==T_STEPS-1){
        cout[hr0+tid]=c_st;
        if(fh_out) fh_out[hr0+tid]=h_st;
      }
    }
    // no 3rd barrier: gl reads above complete before any thread passes the
    // NEXT iteration's first __syncthreads, which precedes all gl writes.
  }
}

// Fused layer pair: blocks [0,128) = layer A, [128,256) = layer B.
// B consumes A's stream with 1-step skew. A never waits on B.
__global__ __launch_bounds__(512,2) void lstm_scan_pair(
    const float* __restrict__ xinA,
    const u64*  __restrict__ insA, u64* __restrict__ ownA, u32 miA, u32 moA,
    const float* __restrict__ WihA, const float* __restrict__ WhhA,
    const float* __restrict__ bihA, const float* __restrict__ bhhA,
    const float* __restrict__ c0A, float* __restrict__ coutA,
    const u64*  __restrict__ h0A, float* __restrict__ fhA, int modeA,
    const u64*  __restrict__ insB, u64* __restrict__ ownB, u32 miB, u32 moB,
    const float* __restrict__ WihB, const float* __restrict__ WhhB,
    const float* __restrict__ bihB, const float* __restrict__ bhhB,
    const float* __restrict__ c0B, float* __restrict__ coutB,
    const u64*  __restrict__ h0B, float* __restrict__ fhB, int modeB,
    u32* __restrict__ panic)
{
  __shared__ __align__(16) float st[2304];
  __shared__ float gl[32];
  const int b=blockIdx.x, tid=threadIdx.x;
  if(b<128){
    lstm_scan_body(b, tid, st, gl, xinA, insA, ownA, miA, moA,
                   WihA, WhhA, bihA, bhhA, c0A, coutA, h0A, fhA, panic, modeA);
  } else {
    lstm_scan_body(b-128, tid, st, gl, nullptr, insB, ownB, miB, moB,
                   WihB, WhhB, bihB, bhhB, c0B, coutB, h0B, fhB, panic, modeB);
  }
}

// out[(4095-tp), o] = leaky( sum_k oW[o,k] * h1d[tp][k] + ob[o] )
__global__ __launch_bounds__(256) void proj_out(
    const u64* __restrict__ SB, const float* __restrict__ oW,
    const float* __restrict__ ob, float* __restrict__ out)
{
  __shared__ __align__(16) float hb[1024];
  const int tp=blockIdx.x, tid=threadIdx.x;
  #pragma unroll
  for(int j=0;j<4;j++)
    hb[tid*4+j] = untag1(SB[(size_t)(tp+1)*SLOT_U64 + tid*4 + j]);
  __syncthreads();
  #pragma unroll
  for(int j=0;j<4;j++){
    int o = tid + 256*j;
    const float* wr = oW + (size_t)o*H_DIM;
    float acc=0.f;
    for(int k=0;k<1024;k+=4){
      float4 wv=*(const float4*)(wr+k);
      acc += wv.x*hb[k]+wv.y*hb[k+1]+wv.z*hb[k+2]+wv.w*hb[k+3];
    }
    acc += ob[o];
    acc = acc>0.f ? acc : 0.01f*acc;
    out[(size_t)(4095-tp)*H_DIM + o]=acc;
  }
}

extern "C" void kernel_launch(void* const* d_in, const int* in_sizes, int n_in,
                              void* d_out, int out_size, void* d_ws, size_t ws_size,
                              hipStream_t stream) {
  const float* x    = (const float*)d_in[0];
  const float* eWih = (const float*)d_in[1];
  const float* eWhh = (const float*)d_in[2];
  const float* ebih = (const float*)d_in[3];
  const float* ebhh = (const float*)d_in[4];
  const float* dWih = (const float*)d_in[5];
  const float* dWhh = (const float*)d_in[6];
  const float* dbih = (const float*)d_in[7];
  const float* dbhh = (const float*)d_in[8];
  const float* oW   = (const float*)d_in[9];
  const float* ob   = (const float*)d_in[10];
  float* out = (float*)d_out;
  u32* ws = (u32*)d_ws;

  const size_t REGION = (size_t)NSLOT*SLOT_DW;     // in dwords
  u64*   SA    = (u64*)ws;
  u64*   SB    = (u64*)(ws + REGION);
  float* CA    = (float*)(ws + 2*REGION);          // 2048 floats: enc c finals
  u32*   panic = ws + 2*REGION + 2048;
  const size_t LSTRIDE = (size_t)4096*1024;        // per-layer weight stride

  // clear tags + c buffer + panic
  size_t clr_bytes = (2*REGION + 2048 + 64)*4;
  hipMemsetAsync(d_ws, 0, clr_bytes, stream);

  // Phase 1: enc L0 (mode 0, x -> SA/M1, zero init) || enc L1 (mode 1,
  // SA/M1 -> SB/M1, zero init, writes final_hidden).
  lstm_scan_pair<<<256,512,0,stream>>>(
      x, nullptr, SA, 0u, M1,
      eWih, eWhh, ebih, ebhh,
      nullptr, CA, nullptr, nullptr, 0,
      SA, SB, M1, M1,
      eWih+LSTRIDE, eWhh+LSTRIDE, ebih+4096, ebhh+4096,
      nullptr, CA+1024, nullptr, out + (size_t)T_STEPS*H_DIM, 1,
      panic);

  // Phase 2: dec L0 (mode 2, const input = final_hidden slot SB[4096],
  // stream SA reused with M2, init = enc L0 finals) || dec L1 (mode 3,
  // SA/M2 -> SB/M2, init = enc L1 finals).
  lstm_scan_pair<<<256,512,0,stream>>>(
      nullptr, SB + (size_t)4096*SLOT_U64, SA, 0u, M2,
      dWih, dWhh, dbih, dbhh,
      CA, CA, SA + (size_t)4096*SLOT_U64, nullptr, 2,
      SA, SB, M2, M2,
      dWih+LSTRIDE, dWhh+LSTRIDE, dbih+4096, dbhh+4096,
      CA+1024, CA+1024, SB + (size_t)4096*SLOT_U64, nullptr, 3,
      panic);

  // projection + leaky ReLU + flip
  proj_out<<<4096,256,0,stream>>>(SB, oW, ob, out);
}